// Round 2
// baseline (303740.723 us; speedup 1.0000x reference)
//
#include <hip/hip_runtime.h>
#include <hip/hip_fp16.h>
#include <stdint.h>
#include <string.h>

#define RES      8192
#define IN_DIM   64
#define DYN      1000
#define TOT      2000

#define BLOCKS   512
#define TPB      1024
#define WPB      16          // waves per block

// Output layout (floats):
//   prediction          [     0 ..  63999]
//   target              [ 64000 .. 127999]  copy of input[1000:2000]
//   prediction_augment  [128000 .. 255999]
//   target_augment      [256000 .. 383999]  copy of input
//
// ws layout (float indices). Sync lines padded to 128 B. Cross-block sync
// uses relaxed agent-scope atomics. h broadcast: RING mode uses one-shot
// buffers in DESCENDING-t memory order (virgin addresses -> normal cached
// loads legal + any forward-sequential speculative fill lands on an OLDER,
// immutable slot); fallback DBUF mode uses the cache-bypass double buffer.
#define WS_OUT      0              // outbuf [64]
#define WS_DONE     64             // 64 producer-done slots x 32
#define WS_FLAG     2112           // 32 flag copies x 32
#define WS_GEN      3136           // 32 gen copies x 32
#define WS_SLOT     4160           // 512 arrival slots x 32
#define WS_SYNC_END 20544          // end of sync area (zeroed in ring mode)
#define WS_H0       20544          // dbuf slot 0 [8192]  (non-ring)
#define WS_H1       28736          // dbuf slot 1 [8192]  (non-ring)
#define WS_TOTAL    36928          // zero range, non-ring
#define WS_RING     36928          // ring: 2001 x 8192 floats; slot(t) = TOT - t
#define WS_RING_END (WS_RING + 2001 * RES)   // 16429120
#define WS_WH16_DBUF 40960         // fp16 W_h in dbuf mode (old layout)

__global__ void copy_targets(const float* __restrict__ input, float* __restrict__ out) {
    int i = blockIdx.x * blockDim.x + threadIdx.x;
    if (i < 64000)  out[64000 + i]  = input[64000 + i];   // target
    if (i < 128000) out[256000 + i] = input[i];           // target_augment
}

// fp32 -> fp16 conversion of W_h (67.1M elems).
__global__ void convert_wh(const float* __restrict__ W_h, __half2* __restrict__ w16) {
    const float4* src = (const float4*)W_h;
    const int stride = gridDim.x * blockDim.x;
    for (int j = blockIdx.x * blockDim.x + threadIdx.x;
         j < RES * RES / 4; j += stride) {
        float4 v = src[j];
        w16[2 * j]     = __floats2half2_rn(v.x, v.y);
        w16[2 * j + 1] = __floats2half2_rn(v.z, v.w);
    }
}

__device__ __forceinline__ unsigned ld_u32(const unsigned* p) {
    return __hip_atomic_load(p, __ATOMIC_RELAXED, __HIP_MEMORY_SCOPE_AGENT);
}
__device__ __forceinline__ void st_u32(unsigned* p, unsigned v) {
    __hip_atomic_store(p, v, __ATOMIC_RELAXED, __HIP_MEMORY_SCOPE_AGENT);
}
__device__ __forceinline__ float ld_f32(const float* p) {
    return __hip_atomic_load(p, __ATOMIC_RELAXED, __HIP_MEMORY_SCOPE_AGENT);
}
__device__ __forceinline__ void st_f32(float* p, float v) {
    __hip_atomic_store(p, v, __ATOMIC_RELAXED, __HIP_MEMORY_SCOPE_AGENT);
}
__device__ __forceinline__ uint64_t ld_u64(const uint64_t* p) {
    return __hip_atomic_load(p, __ATOMIC_RELAXED, __HIP_MEMORY_SCOPE_AGENT);
}
__device__ __forceinline__ float2 h2f2(unsigned u) {
    __half2 h;
    *reinterpret_cast<unsigned*>(&h) = u;
    return __half22float2(h);
}

// LDS swizzle: permute 16-B chunks, p(c) = c ^ ((c>>3)&7). Involution; spreads
// the W_h-dot read pattern (byte 32*lane -> 16-way conflict) uniformly over
// all 8 bank groups. Applied to ALL h_lds writers and readers.

template <bool FP16, bool RING>
__global__ __launch_bounds__(TPB, 8) void esn_kernel(
    const float* __restrict__ input,   // 2000 x 64
    const float* __restrict__ W_in,    // 8192 x 64
    const float* __restrict__ W_h,     // 8192 x 8192 (fp32, used when !FP16)
    const float* __restrict__ W_out,   // 64 x 8192
    float* __restrict__ out,
    float* __restrict__ ws,
    const __half2* __restrict__ wh16)
{
    __shared__ __align__(16) float h_lds[RES];
    __shared__ float xbuf[IN_DIM];

    float*    outbuf = ws + WS_OUT;
    unsigned* done   = (unsigned*)(ws + WS_DONE);
    unsigned* flag   = (unsigned*)(ws + WS_FLAG);
    unsigned* gen    = (unsigned*)(ws + WS_GEN);
    unsigned* slot   = (unsigned*)(ws + WS_SLOT);
    float*    hring  = ws + WS_RING;
    float*    hbuf0  = ws + WS_H0;
    float*    hbuf1  = ws + WS_H1;

    float* pred    = out;            // prediction
    float* aug_out = out + 128000;   // prediction_augment

    const int tid  = threadIdx.x;
    const int lane = tid & 63;
    const int wid  = tid >> 6;
    const int bid  = blockIdx.x;
    const int r    = bid * WPB + wid;          // this wave's W_h row

    // constant per-thread operands, hoisted out of the time loop
    const float w_in_l = W_in[(size_t)r * IN_DIM + lane];

    // swizzled LDS read bases (constant per thread; per-iter offsets are
    // compile-time immediates folded into ds_read offset:)
    const int   mmA = (lane >> 2) & 7;
    const float4* hA0 = (const float4*)h_lds + ((2 * lane)     ^ mmA);
    const float4* hB0 = (const float4*)h_lds + ((2 * lane + 1) ^ mmA);
    const int   ppr = lane ^ ((lane >> 3) & 7);   // float4-granular pattern

    const uint4* wrow4 = (const uint4*)(wh16 + (size_t)r * (RES / 2));

    // W_h row register prefetch (iters 0..3); re-issued inside the grid
    // barrier each step so the loads fly during the poll/stage window.
    uint4 pf0, pf1, pf2, pf3;
    if constexpr (FP16) {
        pf0 = wrow4[lane];       pf1 = wrow4[lane + 64];
        pf2 = wrow4[lane + 128]; pf3 = wrow4[lane + 192];
    }

    for (int t = 0; t < TOT; ++t) {
        // ---- stage h_t into LDS (swizzled destination) ----
        if constexpr (RING) {
            const float4* src = (const float4*)(hring + (size_t)(TOT - t) * RES);
            float4* dst = (float4*)h_lds;
            const int sw = (tid >> 3) & 7;
            #pragma unroll
            for (int i = 0; i < RES / 4 / TPB; ++i) {     // 2 iters
                const int c = tid + i * TPB;
                dst[c ^ sw] = src[c];                      // cached load, L2 dedup
            }
        } else {
            const float* hcur = (t & 1) ? hbuf1 : hbuf0;
            const uint64_t* src = (const uint64_t*)hcur;
            uint64_t*       dst = (uint64_t*)h_lds;
            const int du = ((((tid >> 1) ^ ((tid >> 4) & 7)) << 1) | (tid & 1));
            #pragma unroll
            for (int i = 0; i < RES / 2 / TPB; ++i)        // 4 iters
                dst[du + i * TPB] = ld_u64(src + tid + i * TPB);
        }
        __syncthreads();

        // ---- producers: out_t[j] = W_out[j] @ aug(h_t), wave 1 of blocks 0..63 ----
        if (wid == 1 && bid < 64 && t >= 1) {
            const int j = bid;
            const float* wrow = W_out + (size_t)j * RES;
            float acc = 0.f;
            #pragma unroll 8
            for (int i = 0; i < RES / 256; ++i) {
                float4 w = *(const float4*)(wrow + 4 * (lane + 64 * i));
                float4 h = ((const float4*)h_lds)[ppr + 64 * i];
                // aug: even index -> h*h, odd -> h (chunk base is 16-B aligned)
                acc += w.x * h.x * h.x + w.y * h.y + w.z * h.z * h.z + w.w * h.w;
            }
            #pragma unroll
            for (int off = 32; off; off >>= 1) acc += __shfl_xor(acc, off, 64);
            if (lane == 0) {
                if (t <= DYN)  aug_out[(size_t)(t - 1) * 64 + j] = acc;  // warm_up[t-1]
                if (t >= DYN) {
                    pred[(size_t)(t - DYN) * 64 + j] = acc;              // prediction
                    aug_out[(size_t)t * 64 + j]      = acc;              // aug[t]
                    st_f32(outbuf + j, acc);                             // fed back
                    __builtin_amdgcn_s_waitcnt(0);      // outbuf visible before done
                    st_u32(done + j * 32, (unsigned)(t - DYN + 1));
                }
            }
        }

        // ---- aggregator: wave 0 of block 64 collects done slots, fans flag out ----
        if (wid == 0 && bid == 64 && t >= DYN && t < TOT - 1) {
            const unsigned p = (unsigned)(t - DYN + 1);
            for (;;) {
                unsigned v = ld_u32(done + lane * 32);    // 64 distinct lines
                if (__all((int)(v >= p))) break;
                __builtin_amdgcn_s_sleep(2);
            }
            __builtin_amdgcn_s_waitcnt(0);
            if (lane < 32) st_u32(flag + lane * 32, p);
        }

        if (t == TOT - 1) break;   // last h-update is never consumed

        // ---- h_{t+1}[r] = tanh(W_in[r] @ x_t + W_h[r] @ h_t) ----
        {
            float a0 = 0.f, a1 = 0.f, a2 = 0.f, a3 = 0.f;
            if constexpr (FP16) {
                #pragma unroll
                for (int i = 0; i < RES / 512; ++i) {      // 16 iters
                    uint4 wv;
                    switch (i) {
                        case 0: wv = pf0; break;
                        case 1: wv = pf1; break;
                        case 2: wv = pf2; break;
                        case 3: wv = pf3; break;
                        default: wv = wrow4[lane + 64 * i];
                    }
                    float4 hA = hA0[128 * i];
                    float4 hB = hB0[128 * i];
                    float2 f0 = h2f2(wv.x);
                    float2 f1 = h2f2(wv.y);
                    float2 f2 = h2f2(wv.z);
                    float2 f3 = h2f2(wv.w);
                    a0 += f0.x * hA.x; a1 += f0.y * hA.y;
                    a2 += f1.x * hA.z; a3 += f1.y * hA.w;
                    a0 += f2.x * hB.x; a1 += f2.y * hB.y;
                    a2 += f3.x * hB.z; a3 += f3.y * hB.w;
                }
            } else {
                const float* wrow = W_h + (size_t)r * RES;
                #pragma unroll 8
                for (int i = 0; i < RES / 256; ++i) {      // 32 iters
                    float4 w = *(const float4*)(wrow + 4 * (lane + 64 * i));
                    float4 h = ((const float4*)h_lds)[ppr + 64 * i];
                    a0 += w.x * h.x; a1 += w.y * h.y;
                    a2 += w.z * h.z; a3 += w.w * h.w;
                }
            }
            float acc = (a0 + a2) + (a1 + a3);

            // x only needed now: warm -> input row; pred -> wait for flag
            // (overlapped with the whole W_h row load above), thread 0 polls.
            float x_l;
            if (t < DYN) {
                x_l = input[(size_t)t * IN_DIM + lane];
            } else {
                const unsigned p = (unsigned)(t - DYN + 1);
                __syncthreads();
                if (tid == 0) {
                    while (ld_u32(flag + (bid & 31) * 32) < p)
                        __builtin_amdgcn_s_sleep(2);
                }
                __syncthreads();
                if (tid < IN_DIM) xbuf[tid] = ld_f32(outbuf + tid);
                __syncthreads();
                x_l = xbuf[lane];
            }
            acc += w_in_l * x_l;

            #pragma unroll
            for (int off = 32; off; off >>= 1) acc += __shfl_xor(acc, off, 64);
            if (lane == 0) {
                const float hv = tanhf(acc);
                if constexpr (RING)
                    st_f32(hring + (size_t)(TOT - 1 - t) * RES + r, hv);  // slot(t+1)
                else
                    st_f32(((t & 1) ? hbuf0 : hbuf1) + r, hv);
            }
        }

        // ---- grid barrier: drain own stores, per-block slot store (no RMW),
        //      block 0 scans 512 distinct lines, fans gen out to 32 copies.
        //      W_h prefetch for step t+1 is issued here so it overlaps the
        //      poll + stage window. ----
        __builtin_amdgcn_s_waitcnt(0);
        __syncthreads();
        const unsigned e = (unsigned)(t + 1);
        if (tid == 0) st_u32(slot + bid * 32, e);
        if constexpr (FP16) {
            pf0 = wrow4[lane];       pf1 = wrow4[lane + 64];
            pf2 = wrow4[lane + 128]; pf3 = wrow4[lane + 192];
        }
        if (bid == 0) {
            unsigned v = e;
            for (;;) {
                if (tid < BLOCKS) v = ld_u32(slot + tid * 32);
                if (__syncthreads_and(tid >= BLOCKS || v >= e)) break;
                __builtin_amdgcn_s_sleep(2);
            }
            if (tid < 32) st_u32(gen + tid * 32, e);
        } else {
            if (tid == 0) {
                while (ld_u32(gen + (bid & 31) * 32) < e)
                    __builtin_amdgcn_s_sleep(4);
            }
            __syncthreads();
        }
    }
}

extern "C" void kernel_launch(void* const* d_in, const int* in_sizes, int n_in,
                              void* d_out, int out_size, void* d_ws, size_t ws_size,
                              hipStream_t stream) {
    const float* input = (const float*)d_in[0];
    const float* W_in  = (const float*)d_in[1];
    const float* W_h   = (const float*)d_in[2];
    const float* W_out = (const float*)d_in[3];
    float* out = (float*)d_out;
    float* ws  = (float*)d_ws;

    copy_targets<<<dim3((128000 + 255) / 256), dim3(256), 0, stream>>>(input, out);

    const size_t need_ring = (size_t)WS_RING_END * sizeof(float)
                           + (size_t)RES * RES * sizeof(__half);
    const size_t need_dbuf = (size_t)WS_WH16_DBUF * sizeof(float)
                           + (size_t)RES * RES * sizeof(__half);

    if (ws_size >= need_ring) {
        // zero the sync area and ring slot(t=0) = slot index TOT (h0 = zeros)
        hipMemsetAsync(d_ws, 0, (size_t)WS_SYNC_END * sizeof(float), stream);
        hipMemsetAsync(ws + WS_RING + (size_t)TOT * RES, 0,
                       (size_t)RES * sizeof(float), stream);
        __half2* w16 = (__half2*)(ws + WS_RING_END);
        convert_wh<<<dim3(2048), dim3(1024), 0, stream>>>(W_h, w16);
        esn_kernel<true, true><<<dim3(BLOCKS), dim3(TPB), 0, stream>>>(
            input, W_in, W_h, W_out, out, ws, w16);
    } else if (ws_size >= need_dbuf) {
        hipMemsetAsync(d_ws, 0, (size_t)WS_TOTAL * sizeof(float), stream);
        __half2* w16 = (__half2*)(ws + WS_WH16_DBUF);
        convert_wh<<<dim3(2048), dim3(1024), 0, stream>>>(W_h, w16);
        esn_kernel<true, false><<<dim3(BLOCKS), dim3(TPB), 0, stream>>>(
            input, W_in, W_h, W_out, out, ws, w16);
    } else {
        hipMemsetAsync(d_ws, 0, (size_t)WS_TOTAL * sizeof(float), stream);
        esn_kernel<false, false><<<dim3(BLOCKS), dim3(TPB), 0, stream>>>(
            input, W_in, W_h, W_out, out, ws, (const __half2*)nullptr);
    }
}

// Round 3
// 60988.684 us; speedup vs baseline: 4.9803x; 4.9803x over previous
//
#include <hip/hip_runtime.h>
#include <hip/hip_fp16.h>
#include <stdint.h>
#include <string.h>

#define RES      8192
#define IN_DIM   64
#define DYN      1000
#define TOT      2000

#define BLOCKS   256         // 1 block/CU -> VGPR budget 128 at 16 waves/CU
#define TPB      1024
#define ROWS_PB  32          // rows per block (2 per wave)

// Output layout (floats):
//   prediction          [     0 ..  63999]
//   target              [ 64000 .. 127999]  copy of input[1000:2000]
//   prediction_augment  [128000 .. 255999]
//   target_augment      [256000 .. 383999]  copy of input
//
// ws layout (float indices). Sync lines padded to 128 B. ALL cross-block
// traffic uses relaxed agent-scope atomics (cache-bypass, coherence-point
// served) -> no fences, no L2 invalidates anywhere.  (Round-0 proven layout.)
#define WS_H0     0              // h buffer 0 [8192]
#define WS_H1     8192           // h buffer 1 [8192]
#define WS_OUT    16384          // outbuf [64]
#define WS_DONE   16448          // 64 producer-done slots x 32
#define WS_FLAG   18496          // 32 flag copies x 32
#define WS_GEN    19520          // 32 gen copies x 32
#define WS_SLOT   20544          // 512 arrival slots x 32 (256 used)
#define WS_TOTAL  36928          // floats to zero
#define WS_WH16   40960          // fp16 W_h starts here (float index; 16-B aligned)

__global__ void copy_targets(const float* __restrict__ input, float* __restrict__ out) {
    int i = blockIdx.x * blockDim.x + threadIdx.x;
    if (i < 64000)  out[64000 + i]  = input[64000 + i];   // target
    if (i < 128000) out[256000 + i] = input[i];           // target_augment
}

// fp32 -> fp16 conversion of W_h (67.1M elems). ~384 MiB of traffic, ~75 us.
__global__ void convert_wh(const float* __restrict__ W_h, __half2* __restrict__ w16) {
    const float4* src = (const float4*)W_h;
    const int stride = gridDim.x * blockDim.x;
    for (int j = blockIdx.x * blockDim.x + threadIdx.x;
         j < RES * RES / 4; j += stride) {
        float4 v = src[j];
        w16[2 * j]     = __floats2half2_rn(v.x, v.y);
        w16[2 * j + 1] = __floats2half2_rn(v.z, v.w);
    }
}

__device__ __forceinline__ unsigned ld_u32(const unsigned* p) {
    return __hip_atomic_load(p, __ATOMIC_RELAXED, __HIP_MEMORY_SCOPE_AGENT);
}
__device__ __forceinline__ void st_u32(unsigned* p, unsigned v) {
    __hip_atomic_store(p, v, __ATOMIC_RELAXED, __HIP_MEMORY_SCOPE_AGENT);
}
__device__ __forceinline__ float ld_f32(const float* p) {
    return __hip_atomic_load(p, __ATOMIC_RELAXED, __HIP_MEMORY_SCOPE_AGENT);
}
__device__ __forceinline__ void st_f32(float* p, float v) {
    __hip_atomic_store(p, v, __ATOMIC_RELAXED, __HIP_MEMORY_SCOPE_AGENT);
}
__device__ __forceinline__ void st_u64(uint64_t* p, uint64_t v) {
    __hip_atomic_store(p, v, __ATOMIC_RELAXED, __HIP_MEMORY_SCOPE_AGENT);
}
__device__ __forceinline__ uint64_t ld_u64(const uint64_t* p) {
    return __hip_atomic_load(p, __ATOMIC_RELAXED, __HIP_MEMORY_SCOPE_AGENT);
}

template <bool FP16>
__global__ __launch_bounds__(TPB, 4) void esn_kernel(
    const float* __restrict__ input,   // 2000 x 64
    const float* __restrict__ W_in,    // 8192 x 64
    const float* __restrict__ W_h,     // 8192 x 8192 (fp32, used when !FP16)
    const float* __restrict__ W_out,   // 64 x 8192
    float* __restrict__ out,
    float* __restrict__ ws)
{
    __shared__ __align__(16) float h_lds[RES];
    __shared__ float xbuf[IN_DIM];

    float*    hbuf0  = ws + WS_H0;
    float*    hbuf1  = ws + WS_H1;
    float*    outbuf = ws + WS_OUT;
    unsigned* done   = (unsigned*)(ws + WS_DONE);
    unsigned* flag   = (unsigned*)(ws + WS_FLAG);
    unsigned* gen    = (unsigned*)(ws + WS_GEN);
    unsigned* slot   = (unsigned*)(ws + WS_SLOT);
    const __half2* wh16 = (const __half2*)(ws + WS_WH16);

    float* pred    = out;            // prediction
    float* aug_out = out + 128000;   // prediction_augment

    const int tid  = threadIdx.x;
    const int lane = tid & 63;
    const int wid  = tid >> 6;
    const int bid  = blockIdx.x;
    const int r0   = bid * ROWS_PB + wid * 2;     // this wave's W_h row pair

    // constant per-thread operands, hoisted out of the time loop
    const float w_in0 = W_in[(size_t)r0 * IN_DIM + lane];
    const float w_in1 = W_in[(size_t)(r0 + 1) * IN_DIM + lane];

    const __half2* wr0 = wh16 + (size_t)r0 * (RES / 2);
    const __half2* wr1 = wr0 + (RES / 2);

    for (int t = 0; t < TOT; ++t) {
        const float* hcur = (t & 1) ? hbuf1 : hbuf0;
        float*       hnxt = (t & 1) ? hbuf0 : hbuf1;

        // ---- stage h_t into LDS via cache-bypass loads (always-fresh) ----
        {
            const uint64_t* src = (const uint64_t*)hcur;
            uint64_t*       dst = (uint64_t*)h_lds;
            #pragma unroll
            for (int i = 0; i < RES / 2 / TPB; ++i)
                dst[tid + i * TPB] = ld_u64(src + tid + i * TPB);
        }
        __syncthreads();

        // ---- producers: out_t[j] = W_out[j] @ aug(h_t), wave 1 of blocks 0..63 ----
        if (wid == 1 && bid < 64 && t >= 1) {
            const int j = bid;
            const float* wrow = W_out + (size_t)j * RES;
            float acc = 0.f;
            #pragma unroll 8
            for (int i = 0; i < RES / 256; ++i) {
                const int k = (lane << 2) + (i << 8);
                float4 w = *(const float4*)(wrow + k);
                float4 h = *(const float4*)(h_lds + k);
                // aug: even index -> h*h, odd -> h (k is a multiple of 4)
                acc += w.x * h.x * h.x + w.y * h.y + w.z * h.z * h.z + w.w * h.w;
            }
            #pragma unroll
            for (int off = 32; off; off >>= 1) acc += __shfl_xor(acc, off, 64);
            if (lane == 0) {
                if (t <= DYN)  aug_out[(size_t)(t - 1) * 64 + j] = acc;  // warm_up[t-1]
                if (t >= DYN) {
                    pred[(size_t)(t - DYN) * 64 + j] = acc;              // prediction
                    aug_out[(size_t)t * 64 + j]      = acc;              // aug[t]
                    st_f32(outbuf + j, acc);                             // fed back
                    __builtin_amdgcn_s_waitcnt(0);      // outbuf visible before done
                    st_u32(done + j * 32, (unsigned)(t - DYN + 1));
                }
            }
        }

        // ---- aggregator: wave 0 of block 64 collects done slots, fans flag out ----
        if (wid == 0 && bid == 64 && t >= DYN && t < TOT - 1) {
            const unsigned p = (unsigned)(t - DYN + 1);
            for (;;) {
                unsigned v = ld_u32(done + lane * 32);    // 64 distinct lines
                if (__all((int)(v >= p))) break;
                __builtin_amdgcn_s_sleep(2);
            }
            __builtin_amdgcn_s_waitcnt(0);
            if (lane < 32) st_u32(flag + lane * 32, p);
        }

        if (t == TOT - 1) break;   // last h-update is never consumed

        // ---- h_{t+1}[r0..r0+1] = tanh(W_in @ x_t + W_h @ h_t), 2 rows/wave ----
        {
            float a00 = 0.f, a01 = 0.f, a02 = 0.f, a03 = 0.f;
            float a10 = 0.f, a11 = 0.f, a12 = 0.f, a13 = 0.f;
            if (FP16) {
                #pragma unroll 8
                for (int i = 0; i < RES / 512; ++i) {
                    // k indexes half2; lane covers 4 half2 = 8 elems = 16 B/row
                    const int k = (lane << 2) + (i << 8);
                    const __half2 w00 = wr0[k + 0];
                    const __half2 w01 = wr0[k + 1];
                    const __half2 w02 = wr0[k + 2];
                    const __half2 w03 = wr0[k + 3];
                    const __half2 w10 = wr1[k + 0];
                    const __half2 w11 = wr1[k + 1];
                    const __half2 w12 = wr1[k + 2];
                    const __half2 w13 = wr1[k + 3];
                    float4 hA = *(const float4*)(h_lds + 2 * k);
                    float4 hB = *(const float4*)(h_lds + 2 * k + 4);
                    float2 f;
                    f = __half22float2(w00); a00 += f.x * hA.x; a01 += f.y * hA.y;
                    f = __half22float2(w01); a02 += f.x * hA.z; a03 += f.y * hA.w;
                    f = __half22float2(w02); a00 += f.x * hB.x; a01 += f.y * hB.y;
                    f = __half22float2(w03); a02 += f.x * hB.z; a03 += f.y * hB.w;
                    f = __half22float2(w10); a10 += f.x * hA.x; a11 += f.y * hA.y;
                    f = __half22float2(w11); a12 += f.x * hA.z; a13 += f.y * hA.w;
                    f = __half22float2(w12); a10 += f.x * hB.x; a11 += f.y * hB.y;
                    f = __half22float2(w13); a12 += f.x * hB.z; a13 += f.y * hB.w;
                }
            } else {
                const float* wrowA = W_h + (size_t)r0 * RES;
                const float* wrowB = wrowA + RES;
                #pragma unroll 8
                for (int i = 0; i < RES / 256; ++i) {
                    const int k = (lane << 2) + (i << 8);
                    float4 w0 = *(const float4*)(wrowA + k);
                    float4 w1 = *(const float4*)(wrowB + k);
                    float4 h = *(const float4*)(h_lds + k);
                    a00 += w0.x * h.x; a01 += w0.y * h.y;
                    a02 += w0.z * h.z; a03 += w0.w * h.w;
                    a10 += w1.x * h.x; a11 += w1.y * h.y;
                    a12 += w1.z * h.z; a13 += w1.w * h.w;
                }
            }
            float acc0 = (a00 + a02) + (a01 + a03);
            float acc1 = (a10 + a12) + (a11 + a13);

            // x only needed now: warm -> input row; pred -> wait for flag
            // (overlapped with the whole W_h row-pair load above), thread 0 polls.
            float x_l;
            if (t < DYN) {
                x_l = input[(size_t)t * IN_DIM + lane];
            } else {
                const unsigned p = (unsigned)(t - DYN + 1);
                __syncthreads();
                if (tid == 0) {
                    while (ld_u32(flag + (bid & 31) * 32) < p)
                        __builtin_amdgcn_s_sleep(2);
                }
                __syncthreads();
                if (tid < IN_DIM) xbuf[tid] = ld_f32(outbuf + tid);
                __syncthreads();
                x_l = xbuf[lane];
            }
            acc0 += w_in0 * x_l;
            acc1 += w_in1 * x_l;

            #pragma unroll
            for (int off = 32; off; off >>= 1) {
                acc0 += __shfl_xor(acc0, off, 64);
                acc1 += __shfl_xor(acc1, off, 64);
            }
            if (lane == 0) {
                float2 hv;
                hv.x = tanhf(acc0);
                hv.y = tanhf(acc1);
                uint64_t u;
                memcpy(&u, &hv, 8);
                st_u64((uint64_t*)(hnxt + r0), u);   // r0 even -> 8-B aligned
            }
        }

        // ---- grid barrier: drain own stores, per-block slot store (no RMW),
        //      block 0 scans 256 distinct lines, fans gen out to 32 copies ----
        __builtin_amdgcn_s_waitcnt(0);
        __syncthreads();
        const unsigned e = (unsigned)(t + 1);
        if (tid == 0) st_u32(slot + bid * 32, e);
        if (bid == 0) {
            unsigned v = e;
            for (;;) {
                if (tid < BLOCKS) v = ld_u32(slot + tid * 32);
                if (__syncthreads_and(tid >= BLOCKS || v >= e)) break;
                __builtin_amdgcn_s_sleep(2);
            }
            if (tid < 32) st_u32(gen + tid * 32, e);
        } else {
            if (tid == 0) {
                while (ld_u32(gen + (bid & 31) * 32) < e)
                    __builtin_amdgcn_s_sleep(4);
            }
            __syncthreads();
        }
    }
}

extern "C" void kernel_launch(void* const* d_in, const int* in_sizes, int n_in,
                              void* d_out, int out_size, void* d_ws, size_t ws_size,
                              hipStream_t stream) {
    const float* input = (const float*)d_in[0];
    const float* W_in  = (const float*)d_in[1];
    const float* W_h   = (const float*)d_in[2];
    const float* W_out = (const float*)d_in[3];
    float* out = (float*)d_out;
    float* ws  = (float*)d_ws;

    // sync area + h buffers must start at zero (ws is poisoned 0xAA each call)
    hipMemsetAsync(d_ws, 0, WS_TOTAL * sizeof(float), stream);

    copy_targets<<<dim3((128000 + 255) / 256), dim3(256), 0, stream>>>(input, out);

    const size_t need = (size_t)WS_WH16 * sizeof(float)
                      + (size_t)RES * RES * sizeof(__half);
    if (ws_size >= need) {
        // fp16 W_h (128 MiB -> fully Infinity-Cache-resident)
        convert_wh<<<dim3(2048), dim3(1024), 0, stream>>>(
            W_h, (__half2*)(ws + WS_WH16));
        esn_kernel<true><<<dim3(BLOCKS), dim3(TPB), 0, stream>>>(
            input, W_in, W_h, W_out, out, ws);
    } else {
        // fallback: fp32 path
        esn_kernel<false><<<dim3(BLOCKS), dim3(TPB), 0, stream>>>(
            input, W_in, W_h, W_out, out, ws);
    }
}